// Round 14
// baseline (205.728 us; speedup 1.0000x reference)
//
#include <hip/hip_runtime.h>

// out[e,i] = sum_j mat[e,i,j] v[e,j] + bias[e,i],  [mat|bias] = MLP(pos).reshape(32,33)
// Round-15: 8 waves x 32 edges (512-thread blocks) -> af[2][4]=32 regs -> total
// per-wave demand ~90-100 -> fits __launch_bounds__(512,4)'s 128 budget ->
// 4 waves/SIMD (2 blocks/CU). r11 showed wall ~ 1/waves; r13 showed P=46us is
// latency-bound at 2 waves/SIMD. B staged to LDS per block (r4 global_load_lds
// 2-tile double-buffer, 1 barrier/chunk; 1 load/thread/chunk at 512 thr) to keep
// L2 traffic at 1x per block (per-wave reg-B at 8 waves would double it to ~62us
// of L2 time). oa-init deferred past prologue (arch-pressure, r8 lesson).
//   P[e, col] = h2[e,0:128] @ Wpack[0:128, col]   (col = j*32+i; W3-only)
//   out[e,i]  = sum_{col: i} vext[e,j] * P[e,col] + (b3 mini-GEMM)
// LDS: prologue h1c[64][136] @0, h2n[64][136] @17408 (34816); G-loop vt[33][260] @0
//      (34320, overlays); Bb u16[2][4096] @34816 (16384). Static 51200 B.
// ws: Wg2 @0 (270336), W2f @270336 (32768), b3f @303104 (2048), b3c @305152 (128).

#define E_TOTAL 262144
#define EPB 256
#define NBLK (E_TOTAL / EPB)

typedef float f32x4 __attribute__((ext_vector_type(4)));
typedef short s8v  __attribute__((ext_vector_type(8)));
typedef short s4v  __attribute__((ext_vector_type(4)));
typedef unsigned int u32;

__device__ __forceinline__ unsigned short f2bf(float x) {
  unsigned u = __float_as_uint(x);
  u += 0x7fffu + ((u >> 16) & 1u);
  return (unsigned short)(u >> 16);
}

__device__ __forceinline__ void ld16_g2l(const void* g, void* l) {
  __builtin_amdgcn_global_load_lds((const __attribute__((address_space(1))) u32*)g,
                                   (__attribute__((address_space(3))) u32*)l, 16, 0, 0);
}

// ---------------- prep: pack W2/W3/b3 into MFMA B-fragment order ----------------
// Coalesced f32 reads, scattered bf16 writes (r7 version, verified).
__global__ void prep_pack(const float* __restrict__ W2, const float* __restrict__ W3,
                          const float* __restrict__ b3,
                          unsigned short* __restrict__ Wg2, unsigned short* __restrict__ W2f,
                          unsigned short* __restrict__ b3f, float* __restrict__ b3c) {
  int idx = blockIdx.x * 256 + threadIdx.x;   // 528 blocks cover 135168
  if (idx < 135168) {
    int k = idx / 1056, c = idx % 1056;
    int i = c / 33, jc = c % 33;
    int col = jc * 32 + i;                    // Wg2 col = j*32 + i
    int nnt = col >> 4, low = col & 15;
    int nn = (nnt & 1) ? (33 + (nnt >> 1)) : (nnt >> 1);   // permuted tile order
    int ks = k >> 5, kr = k & 31;
    int lane = ((kr >> 3) << 4) + low;
    int jj = k & 7;
    Wg2[((nn * 4 + ks) * 64 + lane) * 8 + jj] = f2bf(W3[idx]);
  }
  if (idx < 16384) {
    int k = idx >> 7, n = idx & 127;
    int ks = k >> 5, kr = k & 31;
    int nt = n >> 4, low = n & 15;
    int l = ((kr >> 3) << 4) + low;
    int jj = k & 7;
    W2f[((ks * 8 + nt) * 64 + l) * 8 + jj] = f2bf(W2[idx]);
  }
  if (idx < 1024) {
    int jj = idx & 7, lane = (idx >> 3) & 63, ih = idx >> 9;
    int j = ((lane >> 4) << 3) + jj, i = ih * 16 + (lane & 15);
    b3f[idx] = f2bf(b3[i * 33 + j]);
  }
  if (idx < 32) b3c[idx] = b3[idx * 33 + 32];
}

// ---------------- G-loop tile compute (per-wave 32 edges: m = 0..1) ----------------
template <int IH>
__device__ __forceinline__ void tile_compute(const unsigned short* __restrict__ buf, int t,
                                             const float* __restrict__ vt, int j,
                                             int w, int q, int lane,
                                             const s8v (&af)[2][4], float (&oa)[2][2][4]) {
  const f32x4 zero4 = {0.f, 0.f, 0.f, 0.f};
  s8v bfr[4];
#pragma unroll
  for (int ks = 0; ks < 4; ++ks)
    bfr[ks] = *(const s8v*)&buf[(t * 4 + ks) * 512 + lane * 8];
  const float* vp = vt + j * 260 + w * 32 + q * 4;
#pragma unroll
  for (int m = 0; m < 2; ++m) {
    f32x4 p = __builtin_amdgcn_mfma_f32_16x16x32_bf16(af[m][0], bfr[0], zero4, 0, 0, 0);
#pragma unroll
    for (int ks = 1; ks < 4; ++ks)
      p = __builtin_amdgcn_mfma_f32_16x16x32_bf16(af[m][ks], bfr[ks], p, 0, 0, 0);
    f32x4 vv = *(const f32x4*)(vp + m * 16);
#pragma unroll
    for (int r = 0; r < 4; ++r) oa[IH][m][r] += vv[r] * p[r];
  }
}

// ---------------- fused main kernel ----------------
// 512 threads (8 waves), 256 edges/block; wave w owns edges [B0+w*32, B0+w*32+32).
__global__ __launch_bounds__(512, 4) void fnn_fused(
    const float* __restrict__ pos_i, const float* __restrict__ pos_j,
    const float* __restrict__ vj, const float* __restrict__ W1,
    const float* __restrict__ b1, const float* __restrict__ b2,
    const unsigned short* __restrict__ W2f, const unsigned short* __restrict__ Wg2,
    const unsigned short* __restrict__ b3f, const float* __restrict__ b3c,
    float* __restrict__ out) {
  __shared__ __attribute__((aligned(16))) char smem[51200];
  float* vt = (float*)smem;                                  // [33][260], G-loop phase
  unsigned short* h1c = (unsigned short*)smem;               // [64][136], prologue
  unsigned short* h2n = (unsigned short*)(smem + 17408);     // [64][136], prologue
  unsigned short* Bb  = (unsigned short*)(smem + 34816);     // [2][4096], G-loop
  char* BbChar = smem + 34816;

  const int tid = threadIdx.x;
  const int w = tid >> 6, lane = tid & 63, q = lane >> 4, ln = lane & 15;
  const int B0 = blockIdx.x * EPB;

  // --- W1/b1 register slice: thread owns 4 hidden cols (16+4 regs) ---
  const int hh0 = (tid & 31) * 4;
  float w1r[4][4], b1r4[4];
#pragma unroll
  for (int d = 0; d < 4; ++d)
#pragma unroll
    for (int u = 0; u < 4; ++u) w1r[d][u] = W1[d * 128 + hh0 + u];
#pragma unroll
  for (int u = 0; u < 4; ++u) b1r4[u] = b1[hh0 + u];

  // --- stages 1+2 per quarter (64 edges/phase), 2 barriers/qtr ---
  s8v af[2][4];
  for (int qtr = 0; qtr < 4; ++qtr) {
    // stage 1: 512 threads x (4 edges x 4 cols)
#pragma unroll
    for (int half = 0; half < 4; ++half) {
      int ee = (tid >> 5) + half * 16;
      int eg = B0 + qtr * 64 + ee;
      float2 pi = *(const float2*)(pos_i + (size_t)eg * 2);
      float2 pj = *(const float2*)(pos_j + (size_t)eg * 2);
      s4v hv;
#pragma unroll
      for (int u = 0; u < 4; ++u) {
        float o = b1r4[u] + pi.x * w1r[0][u] + pi.y * w1r[1][u] +
                  pj.x * w1r[2][u] + pj.y * w1r[3][u];
        hv[u] = (short)f2bf(fmaxf(o, 0.f));
      }
      *(s4v*)&h1c[ee * 136 + hh0] = hv;
    }
    __syncthreads();   // h1c ready

    // stage 2: 8 waves x 4 tiles: tt = w*4+s covers all 32 (mt,nt) tiles
#pragma unroll
    for (int s = 0; s < 4; ++s) {
      int tt = w * 4 + s, mt = tt >> 3, nt = tt & 7;
      f32x4 a4 = {0.f, 0.f, 0.f, 0.f};
#pragma unroll
      for (int ks = 0; ks < 4; ++ks) {
        s8v afr = *(const s8v*)&h1c[(mt * 16 + ln) * 136 + ks * 32 + q * 8];
        s8v bfr = *(const s8v*)(W2f + ((ks * 8 + nt) * 64 + lane) * 8);
        a4 = __builtin_amdgcn_mfma_f32_16x16x32_bf16(afr, bfr, a4, 0, 0, 0);
      }
      float b2v = b2[nt * 16 + ln];
      int eb = mt * 16 + q * 4;
      int kc = nt * 16 + ln;
#pragma unroll
      for (int r = 0; r < 4; ++r)
        h2n[(eb + r) * 136 + kc] = f2bf(fmaxf(a4[r] + b2v, 0.f));
    }
    __syncthreads();   // h2n ready

    // extraction: wave w's 32 edges live in qtr w>>1, sub-block (w&1)*32
    if ((w >> 1) == qtr) {
#pragma unroll
      for (int m = 0; m < 2; ++m)
#pragma unroll
        for (int ks = 0; ks < 4; ++ks)
          af[m][ks] = *(const s8v*)&h2n[(((w & 1) * 32 + m * 16 + ln)) * 136 + ks * 32 + q * 8];
    }
    // extraction reads complete before this wave crosses the next barrier;
    // next qtr's h2n writes happen only after that barrier -> safe.
  }

  // --- prime chunk 0 into Bb (region disjoint from prologue buffers) ---
  {
    const unsigned short* src = Wg2 + tid * 8;
    char* dstb = BbChar + w * 1024;   // wave-uniform base
    ld16_g2l(src, dstb);
  }
  __syncthreads();   // extraction h2n reads drained before vt overwrite

  // --- oa init via b3 mini-GEMM (w1r dead now; arch pressure low) ---
  float oa[2][2][4];
  {
    s8v av[2];
#pragma unroll
    for (int m = 0; m < 2; ++m) {
      int e = B0 + w * 32 + m * 16 + ln;
      const float4 va = *(const float4*)(vj + (size_t)e * 32 + q * 8);
      const float4 vb = *(const float4*)(vj + (size_t)e * 32 + q * 8 + 4);
      s8v t;
      t[0] = (short)f2bf(va.x); t[1] = (short)f2bf(va.y);
      t[2] = (short)f2bf(va.z); t[3] = (short)f2bf(va.w);
      t[4] = (short)f2bf(vb.x); t[5] = (short)f2bf(vb.y);
      t[6] = (short)f2bf(vb.z); t[7] = (short)f2bf(vb.w);
      av[m] = t;
    }
#pragma unroll
    for (int ih = 0; ih < 2; ++ih) {
      s8v b3fr = *(const s8v*)(b3f + (ih * 64 + lane) * 8);
      float cbv = b3c[ih * 16 + ln];
      f32x4 ci = {cbv, cbv, cbv, cbv};
#pragma unroll
      for (int m = 0; m < 2; ++m) {
        f32x4 p = __builtin_amdgcn_mfma_f32_16x16x32_bf16(av[m], b3fr, ci, 0, 0, 0);
#pragma unroll
        for (int r = 0; r < 4; ++r) oa[ih][m][r] = p[r];
      }
    }
  }

  // --- build vt: vt[j][e] = v[e,j] (f32), row 32 = 1.0 (threads 0..255) ---
  if (tid < 256) {
    const float* vrow = vj + (size_t)(B0 + tid) * 32;
#pragma unroll
    for (int j4 = 0; j4 < 8; ++j4) {
      float4 vv = *(const float4*)(vrow + j4 * 4);
      vt[(j4 * 4 + 0) * 260 + tid] = vv.x;
      vt[(j4 * 4 + 1) * 260 + tid] = vv.y;
      vt[(j4 * 4 + 2) * 260 + tid] = vv.z;
      vt[(j4 * 4 + 3) * 260 + tid] = vv.w;
    }
    vt[32 * 260 + tid] = 1.0f;
  }
  __syncthreads();   // vt ready; implicit vmcnt drain covers chunk-0 staging

  // --- G-loop: 33 chunks x 2 tiles, shared-LDS double-buffer, 1 barrier/chunk ---
#pragma unroll 1
  for (int c = 0; c < 16; ++c) {        // tiles 0..31, IH=0
    const unsigned short* buf = Bb + (c & 1) * 4096;
    {
      const unsigned short* src = Wg2 + (size_t)(c + 1) * 4096 + tid * 8;
      char* dstb = BbChar + ((c + 1) & 1) * 8192 + w * 1024;
      ld16_g2l(src, dstb);
    }
    tile_compute<0>(buf, 0, vt, 2 * c,     w, q, lane, af, oa);
    tile_compute<0>(buf, 1, vt, 2 * c + 1, w, q, lane, af, oa);
    __syncthreads();
  }
  {                                     // straddle chunk 16: tile 32 (IH0), tile 33 (IH1)
    const unsigned short* buf = Bb;     // 16&1 == 0
    {
      const unsigned short* src = Wg2 + (size_t)17 * 4096 + tid * 8;
      char* dstb = BbChar + 8192 + w * 1024;
      ld16_g2l(src, dstb);
    }
    tile_compute<0>(buf, 0, vt, 32, w, q, lane, af, oa);
    tile_compute<1>(buf, 1, vt, 0,  w, q, lane, af, oa);
    __syncthreads();
  }
#pragma unroll 1
  for (int c = 17; c < 33; ++c) {       // tiles 34..65, IH=1
    const unsigned short* buf = Bb + (c & 1) * 4096;
    if (c < 32) {
      const unsigned short* src = Wg2 + (size_t)(c + 1) * 4096 + tid * 8;
      char* dstb = BbChar + ((c + 1) & 1) * 8192 + w * 1024;
      ld16_g2l(src, dstb);
    }
    tile_compute<1>(buf, 0, vt, 2 * c - 33, w, q, lane, af, oa);
    tile_compute<1>(buf, 1, vt, 2 * c - 32, w, q, lane, af, oa);
    __syncthreads();
  }

  // --- epilogue: out[e,i] f32 ---
#pragma unroll
  for (int m = 0; m < 2; ++m)
#pragma unroll
    for (int ih = 0; ih < 2; ++ih)
#pragma unroll
      for (int r = 0; r < 4; ++r) {
        int e = B0 + w * 32 + m * 16 + q * 4 + r;
        out[(size_t)e * 32 + ih * 16 + ln] = oa[ih][m][r];
      }
}

extern "C" void kernel_launch(void* const* d_in, const int* in_sizes, int n_in,
                              void* d_out, int out_size, void* d_ws, size_t ws_size,
                              hipStream_t stream) {
  const float* pos_i = (const float*)d_in[0];
  const float* pos_j = (const float*)d_in[1];
  const float* vj    = (const float*)d_in[2];
  const float* W1    = (const float*)d_in[3];
  const float* b1    = (const float*)d_in[4];
  const float* W2    = (const float*)d_in[5];
  const float* b2    = (const float*)d_in[6];
  const float* W3    = (const float*)d_in[7];
  const float* b3    = (const float*)d_in[8];
  float* outp = (float*)d_out;

  unsigned short* Wg2 = (unsigned short*)d_ws;
  unsigned short* W2f = (unsigned short*)((char*)d_ws + 270336);
  unsigned short* b3f = (unsigned short*)((char*)d_ws + 303104);
  float*          b3c = (float*)((char*)d_ws + 305152);

  prep_pack<<<528, 256, 0, stream>>>(W2, W3, b3, Wg2, W2f, b3f, b3c);
  fnn_fused<<<NBLK, 512, 0, stream>>>(pos_i, pos_j, vj, W1, b1, b2, W2f, Wg2, b3f, b3c, outp);
}